// Round 3
// baseline (193.453 us; speedup 1.0000x reference)
//
#include <hip/hip_runtime.h>
#include <stdint.h>

#define DIM   128
#define NK    512
#define SPB   32768
#define NBLK  1024

#define E_OFF 16777216
#define D_OFF 83886080
#define L_OFF 150994944

typedef __attribute__((ext_vector_type(16))) float f32x16;
typedef __attribute__((ext_vector_type(4)))  float f32x4;
typedef __attribute__((ext_vector_type(8)))  short bf16x8;

__device__ __forceinline__ unsigned int rne_bf16(float f) {
    union { float f; unsigned int u; } v; v.f = f;
    return (v.u + 0x7FFFu + ((v.u >> 16) & 1u)) >> 16;
}
__device__ __forceinline__ float bf16f(unsigned int h) {
    union { float f; unsigned int u; } v; v.u = h << 16;
    return v.f;
}

// Pre-kernel: codebook row sq-norms + 3-way bf16 split in MFMA-fragment-major
// layout: index ((c*8+t)*64 + lane), 8 bf16 per lane = cb[c*32+(l&31)][t*16+(l>>5)*8+j]
__global__ __launch_bounds__(256) void prep_kernel(
        const float* __restrict__ cb, float* __restrict__ ww,
        short* __restrict__ cbh, short* __restrict__ cbm, short* __restrict__ cbl) {
    const int tid = blockIdx.x * 256 + threadIdx.x;   // 0..8191
    if (tid < NK) {
        const float* row = cb + tid * DIM;
        float s = 0.f;
        #pragma unroll 8
        for (int d = 0; d < DIM; ++d) s = fmaf(row[d], row[d], s);
        ww[tid] = s;
    }
    const int l = tid & 63;
    const int t = (tid >> 6) & 7;
    const int c = tid >> 9;
    const float* src = cb + (c * 32 + (l & 31)) * DIM + t * 16 + ((l >> 5) << 3);
    bf16x8 vh, vm, vl;
    #pragma unroll
    for (int j = 0; j < 8; ++j) {
        float f = src[j];
        unsigned int hu = rne_bf16(f);
        float r1 = f - bf16f(hu);
        unsigned int mu = rne_bf16(r1);
        unsigned int lu = rne_bf16(r1 - bf16f(mu));
        vh[j] = (short)hu; vm[j] = (short)mu; vl[j] = (short)lu;
    }
    ((bf16x8*)cbh)[tid] = vh;
    ((bf16x8*)cbm)[tid] = vm;
    ((bf16x8*)cbl)[tid] = vl;
}

__global__ __launch_bounds__(256, 2) void vq_main(
        const float* __restrict__ x, const float* __restrict__ cb,
        const float* __restrict__ ww,
        const short* __restrict__ cbh, const short* __restrict__ cbm,
        const short* __restrict__ cbl,
        float* __restrict__ out, float* __restrict__ partials) {
    // union buffer: x-tile [128][128] / dist stage [128][132] / quant stage [128(d)][132]
    __shared__ float smem[16896];
    __shared__ float xx_s[128];
    __shared__ int   idx_s[128];
    __shared__ float red_s[128];

    const int tid  = threadIdx.x;
    const int bid  = blockIdx.x;
    const int lane = tid & 63;
    const int w    = tid >> 6;
    const int bb   = bid >> 8;            // batch index (256 blocks per batch elem)
    const int s0   = (bid & 255) << 7;    // spatial base
    const int hi4  = (lane >> 5) << 2;

    const float* xb = x + (size_t)bb * (DIM * SPB) + s0;

    // ---- phase 1: stage x tile [d][s] 128x128 f32 (nt loads: read-once stream)
    #pragma unroll
    for (int it = 0; it < 16; ++it) {
        int i4 = tid + it * 256;
        int d  = i4 >> 5;
        int o  = (i4 & 31) << 2;
        f32x4 v = __builtin_nontemporal_load((const f32x4*)(xb + (size_t)d * SPB + o));
        *(f32x4*)(smem + d * 128 + o) = v;
    }
    __syncthreads();

    // ---- phase 2: A fragments in registers (3-way bf16 split), row sq-norms
    bf16x8 ah[8], am[8], al[8];
    {
        const int row = (w << 5) + (lane & 31);
        const int kb  = (lane >> 5) << 3;
        #pragma unroll
        for (int t = 0; t < 8; ++t) {
            bf16x8 vh, vm, vl;
            #pragma unroll
            for (int j = 0; j < 8; ++j) {
                float f = smem[(t * 16 + kb + j) * 128 + row];
                unsigned int hu = rne_bf16(f);
                float r1 = f - bf16f(hu);
                unsigned int mu = rne_bf16(r1);
                unsigned int lu = rne_bf16(r1 - bf16f(mu));
                vh[j] = (short)hu; vm[j] = (short)mu; vl[j] = (short)lu;
            }
            ah[t] = vh; am[t] = vm; al[t] = vl;
        }
    }
    if (tid < 128) {
        float s = 0.f;
        #pragma unroll 8
        for (int d = 0; d < DIM; ++d) {
            float v = smem[d * 128 + tid];
            s = fmaf(v, v, s);
        }
        xx_s[tid] = s;
    }
    __syncthreads();   // xx ready; x-tile LDS dead after this (A is in regs)

    float xxr[16];
    #pragma unroll
    for (int r = 0; r < 16; ++r)
        xxr[r] = xx_s[(w << 5) + (r & 3) + ((r >> 2) << 3) + hi4];

    float bestD[16];
    int   bestI[16];
    #pragma unroll
    for (int r = 0; r < 16; ++r) { bestD[r] = 3.4e38f; bestI[r] = 0; }

    const int col  = lane & 31;
    const int rowl = (w << 5);            // wave's local row base

    // ---- main loop: 4 groups x 4 col-tiles; dist staged in LDS, written
    //      back as f32x4 over 512B-contiguous row spans
    const int tq = tid & 31, t8 = tid >> 5;
    for (int g = 0; g < 4; ++g) {
        for (int cl = 0; cl < 4; ++cl) {
            const int c = (g << 2) + cl;
            f32x16 acc0 = {};
            f32x16 acc1 = {};
            const bf16x8* ph = (const bf16x8*)cbh + c * 512 + lane;
            const bf16x8* pm = (const bf16x8*)cbm + c * 512 + lane;
            const bf16x8* pl = (const bf16x8*)cbl + c * 512 + lane;
            #pragma unroll
            for (int t = 0; t < 8; ++t) {
                bf16x8 bh = ph[t * 64];
                bf16x8 bm = pm[t * 64];
                bf16x8 bl = pl[t * 64];
                acc0 = __builtin_amdgcn_mfma_f32_32x32x16_bf16(ah[t], bh, acc0, 0, 0, 0);
                acc1 = __builtin_amdgcn_mfma_f32_32x32x16_bf16(ah[t], bm, acc1, 0, 0, 0);
                acc0 = __builtin_amdgcn_mfma_f32_32x32x16_bf16(am[t], bh, acc0, 0, 0, 0);
                acc1 = __builtin_amdgcn_mfma_f32_32x32x16_bf16(ah[t], bl, acc1, 0, 0, 0);
                acc0 = __builtin_amdgcn_mfma_f32_32x32x16_bf16(al[t], bh, acc0, 0, 0, 0);
                acc1 = __builtin_amdgcn_mfma_f32_32x32x16_bf16(am[t], bm, acc1, 0, 0, 0);
            }
            const int kcol = (c << 5) + col;
            const float wwc = ww[kcol];
            #pragma unroll
            for (int r = 0; r < 16; ++r) {
                float dot  = acc0[r] + acc1[r];
                float dist = fmaf(-2.f, dot, xxr[r] + wwc);
                int rl = rowl + (r & 3) + ((r >> 2) << 3) + hi4;
                smem[rl * 132 + (cl << 5) + col] = dist;
                bool better = dist < bestD[r];
                bestD[r] = better ? dist : bestD[r];
                bestI[r] = better ? kcol : bestI[r];
            }
        }
        __syncthreads();
        // write-out: each wave instruction covers two full 512B row spans
        #pragma unroll
        for (int q = 0; q < 16; ++q) {
            int row = (q << 3) + t8;
            f32x4 v = *(f32x4*)(smem + row * 132 + (tq << 2));
            __builtin_nontemporal_store(v,
                (f32x4*)(out + (size_t)D_OFF + (size_t)(bid * 128 + row) * NK
                         + (g << 7) + (tq << 2)));
        }
        __syncthreads();
    }

    // ---- argmin: in-register shuffle reduce over the 32-lane column group
    #pragma unroll
    for (int r = 0; r < 16; ++r) {
        float d = bestD[r]; int i = bestI[r];
        #pragma unroll
        for (int m = 16; m >= 1; m >>= 1) {
            float od = __shfl_xor(d, m, 64);
            int   oi = __shfl_xor(i, m, 64);
            if (od < d || (od == d && oi < i)) { d = od; i = oi; }
        }
        bestD[r] = d; bestI[r] = i;
    }
    if ((lane & 31) == 0) {
        #pragma unroll
        for (int r = 0; r < 16; ++r) {
            int row = rowl + (r & 3) + ((r >> 2) << 3) + hi4;
            idx_s[row] = bestI[r];
            red_s[row] = bestD[r];
        }
    }
    __syncthreads();

    // ---- loss partial (wave 0) — deterministic shuffle sum
    if (tid < 64) {
        float s = red_s[tid] + red_s[tid + 64];
        #pragma unroll
        for (int m = 32; m >= 1; m >>= 1) s += __shfl_xor(s, m, 64);
        if (tid == 0) partials[bid] = s;
    }

    // ---- quantized: gather codebook rows transposed into LDS [d][r]
    {
        int r = tid >> 1, h = tid & 1;
        const float* src = cb + idx_s[r] * DIM + h * 64;
        #pragma unroll
        for (int q = 0; q < 16; ++q) {
            f32x4 v = *(const f32x4*)(src + (q << 2));
            int d0 = h * 64 + (q << 2);
            smem[(d0 + 0) * 132 + r] = v[0];
            smem[(d0 + 1) * 132 + r] = v[1];
            smem[(d0 + 2) * 132 + r] = v[2];
            smem[(d0 + 3) * 132 + r] = v[3];
        }
    }
    __syncthreads();

    // ---- quantized store: f32x4, two full 512B d-spans per wave instruction
    {
        float* ob = out + (size_t)bb * (DIM * SPB) + s0;
        #pragma unroll
        for (int q = 0; q < 16; ++q) {
            int d = (q << 3) + t8;
            f32x4 v = *(f32x4*)(smem + d * 132 + (tq << 2));
            __builtin_nontemporal_store(v, (f32x4*)(ob + (size_t)d * SPB + (tq << 2)));
        }
    }

    // ---- encoding one-hot: fused zero+one-hot, lane-contiguous f32x4 nt stores
    {
        float* ebase = out + (size_t)E_OFF + (size_t)bid * (128 * NK);
        #pragma unroll
        for (int j = 0; j < 64; ++j) {
            int v   = j * 256 + tid;       // f32x4 index within block's 128x512 region
            int r   = v >> 7;              // row (broadcast across each wave)
            int cb4 = (v & 127) << 2;      // first col of this vec
            int idxr = idx_s[r];
            f32x4 val;
            val[0] = (idxr == cb4    ) ? 1.0f : 0.0f;
            val[1] = (idxr == cb4 + 1) ? 1.0f : 0.0f;
            val[2] = (idxr == cb4 + 2) ? 1.0f : 0.0f;
            val[3] = (idxr == cb4 + 3) ? 1.0f : 0.0f;
            __builtin_nontemporal_store(val, (f32x4*)ebase + v);
        }
    }
}

__global__ __launch_bounds__(256) void loss_kernel(const float* __restrict__ partials,
                                                   float* __restrict__ out) {
    __shared__ double sd[256];
    int tid = threadIdx.x;
    double s = 0.0;
    for (int i = tid; i < NBLK; i += 256) s += (double)partials[i];
    sd[tid] = s;
    __syncthreads();
    for (int k = 128; k > 0; k >>= 1) {
        if (tid < k) sd[tid] += sd[tid + k];
        __syncthreads();
    }
    if (tid == 0) out[L_OFF] = (float)(2.0 * sd[0] / 16777216.0);
}

extern "C" void kernel_launch(void* const* d_in, const int* in_sizes, int n_in,
                              void* d_out, int out_size, void* d_ws, size_t ws_size,
                              hipStream_t stream) {
    const float* x  = (const float*)d_in[0];
    const float* cb = (const float*)d_in[1];
    float* out = (float*)d_out;
    char*  ws  = (char*)d_ws;
    float* ww  = (float*)ws;                          // 2048 B
    short* cbh = (short*)(ws + 2048);                 // 131072 B
    short* cbm = (short*)(ws + 2048 + 131072);        // 131072 B
    short* cbl = (short*)(ws + 2048 + 262144);        // 131072 B
    float* partials = (float*)(ws + 2048 + 393216);   // 4096 B

    prep_kernel<<<32, 256, 0, stream>>>(cb, ww, cbh, cbm, cbl);
    vq_main<<<NBLK, 256, 0, stream>>>(x, cb, ww, cbh, cbm, cbl, out, partials);
    loss_kernel<<<1, 256, 0, stream>>>(partials, out);
}

// Round 4
// 169.373 us; speedup vs baseline: 1.1422x; 1.1422x over previous
//
#include <hip/hip_runtime.h>
#include <stdint.h>

#define DIM   128
#define NK    512
#define SPB   32768
#define NBLK  1024

#define E_OFF 16777216
#define D_OFF 83886080
#define L_OFF 150994944

typedef __attribute__((ext_vector_type(16))) float f32x16;
typedef __attribute__((ext_vector_type(4)))  float f32x4;
typedef __attribute__((ext_vector_type(8)))  short bf16x8;

__device__ __forceinline__ unsigned int rne_bf16(float f) {
    union { float f; unsigned int u; } v; v.f = f;
    return (v.u + 0x7FFFu + ((v.u >> 16) & 1u)) >> 16;
}
__device__ __forceinline__ float bf16f(unsigned int h) {
    union { float f; unsigned int u; } v; v.u = h << 16;
    return v.f;
}
__device__ __forceinline__ unsigned int f2u(float f) {
    union { float f; unsigned int u; } v; v.f = f; return v.u;
}
__device__ __forceinline__ float u2f(unsigned int u) {
    union { float f; unsigned int u; } v; v.u = u; return v.f;
}

// Pre-kernel: codebook row sq-norms + 2-way bf16 split in MFMA-fragment-major
// layout: index ((c*8+t)*64 + lane), 8 bf16/lane = cb[c*32+(l&31)][t*16+(l>>5)*8+j]
__global__ __launch_bounds__(256) void prep_kernel(
        const float* __restrict__ cb, float* __restrict__ ww,
        short* __restrict__ cbh, short* __restrict__ cbm) {
    const int tid = blockIdx.x * 256 + threadIdx.x;   // 0..8191
    if (tid < NK) {
        const float* row = cb + tid * DIM;
        float s = 0.f;
        #pragma unroll 8
        for (int d = 0; d < DIM; ++d) s = fmaf(row[d], row[d], s);
        ww[tid] = s;
    }
    const int l = tid & 63;
    const int t = (tid >> 6) & 7;
    const int c = tid >> 9;
    const float* src = cb + (c * 32 + (l & 31)) * DIM + t * 16 + ((l >> 5) << 3);
    bf16x8 vh, vm;
    #pragma unroll
    for (int j = 0; j < 8; ++j) {
        float f = src[j];
        unsigned int hu = rne_bf16(f);
        unsigned int mu = rne_bf16(f - bf16f(hu));
        vh[j] = (short)hu; vm[j] = (short)mu;
    }
    ((bf16x8*)cbh)[tid] = vh;
    ((bf16x8*)cbm)[tid] = vm;
}

__global__ __launch_bounds__(256, 3) void vq_main(
        const float* __restrict__ x, const float* __restrict__ cb,
        const float* __restrict__ ww,
        const short* __restrict__ cbh, const short* __restrict__ cbm,
        float* __restrict__ out, float* __restrict__ partials) {
    __shared__ float xx_s[128];
    __shared__ int   idx_s[128];
    __shared__ float red_s[128];

    const int tid  = threadIdx.x;
    const int bid  = blockIdx.x;
    const int lane = tid & 63;
    const int w    = tid >> 6;
    const int bb   = bid >> 8;            // batch index (256 blocks per batch elem)
    const int s0   = (bid & 255) << 7;    // spatial base
    const int hi4  = (lane >> 5) << 2;
    const int rloc = (w << 5) + (lane & 31);   // this lane's x row (0..127)
    const int kb   = (lane >> 5) << 3;         // k-offset 0 or 8

    const float* xrow = x + (size_t)bb * (DIM * SPB) + s0 + rloc;

    // ---- phase 1: direct global fragment loads (nt) + 2-way split + local norm
    bf16x8 ah[8], am[8];
    float xxl = 0.f;
    #pragma unroll
    for (int t = 0; t < 8; ++t) {
        bf16x8 vh, vm;
        #pragma unroll
        for (int j = 0; j < 8; ++j) {
            float f = __builtin_nontemporal_load(xrow + (size_t)(t * 16 + kb + j) * SPB);
            xxl = fmaf(f, f, xxl);
            unsigned int hu = rne_bf16(f);
            unsigned int mu = rne_bf16(f - bf16f(hu));
            vh[j] = (short)hu; vm[j] = (short)mu;
        }
        ah[t] = vh; am[t] = vm;
    }
    // full row norm: lane and lane^32 share a row, complementary k-halves
    xxl += __shfl_xor(xxl, 32, 64);
    if (lane < 32) xx_s[rloc] = xxl;
    __syncthreads();

    float xxr[16];
    #pragma unroll
    for (int r = 0; r < 16; ++r)
        xxr[r] = xx_s[(w << 5) + (r & 3) + ((r >> 2) << 3) + hi4];

    unsigned int best[16];
    #pragma unroll
    for (int r = 0; r < 16; ++r) best[r] = 0xFFFFFFFFu;

    const int col = lane & 31;
    const int rowbase = bid * 128 + (w << 5);

    // ---- main loop: 16 col-tiles of 32 codes; 3-term split MFMA; no barriers
    for (int c = 0; c < 16; ++c) {
        f32x16 acc0 = {};
        f32x16 acc1 = {};
        const bf16x8* ph = (const bf16x8*)cbh + c * 512 + lane;
        const bf16x8* pm = (const bf16x8*)cbm + c * 512 + lane;
        #pragma unroll
        for (int t = 0; t < 8; ++t) {
            bf16x8 bh = ph[t * 64];
            bf16x8 bm = pm[t * 64];
            acc0 = __builtin_amdgcn_mfma_f32_32x32x16_bf16(ah[t], bh, acc0, 0, 0, 0);
            acc1 = __builtin_amdgcn_mfma_f32_32x32x16_bf16(ah[t], bm, acc1, 0, 0, 0);
            acc0 = __builtin_amdgcn_mfma_f32_32x32x16_bf16(am[t], bh, acc0, 0, 0, 0);
        }
        const int kcol = (c << 5) + col;
        const float wwc = ww[kcol];
        #pragma unroll
        for (int r = 0; r < 16; ++r) {
            float dot  = acc0[r] + acc1[r];
            float dist = fmaf(-2.f, dot, xxr[r] + wwc);
            int rl = (r & 3) + ((r >> 2) << 3) + hi4;
            __builtin_nontemporal_store(dist,
                &out[(size_t)D_OFF + (size_t)(rowbase + rl) * NK + kcol]);
            unsigned int pack = (f2u(dist) & ~511u) | (unsigned int)kcol;
            best[r] = pack < best[r] ? pack : best[r];
        }
    }

    // ---- argmin: u32 shuffle-min over the 32-lane column group
    #pragma unroll
    for (int r = 0; r < 16; ++r) {
        unsigned int b = best[r];
        #pragma unroll
        for (int m = 16; m >= 1; m >>= 1) {
            unsigned int ob = __shfl_xor(b, m, 64);
            b = ob < b ? ob : b;
        }
        best[r] = b;
    }
    if ((lane & 31) == 0) {
        #pragma unroll
        for (int r = 0; r < 16; ++r) {
            int row = (w << 5) + (r & 3) + ((r >> 2) << 3) + hi4;
            idx_s[row] = (int)(best[r] & 511u);
            red_s[row] = u2f(best[r] & ~511u);
        }
    }
    __syncthreads();

    // ---- loss partial (wave 0) — deterministic shuffle sum
    if (tid < 64) {
        float s = red_s[tid] + red_s[tid + 64];
        #pragma unroll
        for (int m = 32; m >= 1; m >>= 1) s += __shfl_xor(s, m, 64);
        if (tid == 0) partials[bid] = s;
    }

    // ---- quantized: gather cb row to regs, scalar column stores (2x128B/inst)
    {
        int r = tid >> 1, h = tid & 1;
        const float* src = cb + (size_t)idx_s[r] * DIM + h * 64;
        float* ob = out + (size_t)bb * (DIM * SPB) + s0 + r;
        #pragma unroll
        for (int q = 0; q < 16; ++q) {
            f32x4 v = *(const f32x4*)(src + (q << 2));
            #pragma unroll
            for (int e = 0; e < 4; ++e) {
                int d = h * 64 + (q << 2) + e;
                __builtin_nontemporal_store(v[e], &ob[(size_t)d * SPB]);
            }
        }
    }

    // ---- encoding one-hot: fused zero+one-hot, lane-contiguous f32x4 nt stores
    {
        float* ebase = out + (size_t)E_OFF + (size_t)bid * (128 * NK);
        #pragma unroll
        for (int j = 0; j < 64; ++j) {
            int v   = j * 256 + tid;       // f32x4 index within block's 128x512 region
            int r   = v >> 7;
            int cb4 = (v & 127) << 2;
            int idxr = idx_s[r];
            f32x4 val;
            val[0] = (idxr == cb4    ) ? 1.0f : 0.0f;
            val[1] = (idxr == cb4 + 1) ? 1.0f : 0.0f;
            val[2] = (idxr == cb4 + 2) ? 1.0f : 0.0f;
            val[3] = (idxr == cb4 + 3) ? 1.0f : 0.0f;
            __builtin_nontemporal_store(val, (f32x4*)ebase + v);
        }
    }
}

__global__ __launch_bounds__(256) void loss_kernel(const float* __restrict__ partials,
                                                   float* __restrict__ out) {
    __shared__ double sd[256];
    int tid = threadIdx.x;
    double s = 0.0;
    for (int i = tid; i < NBLK; i += 256) s += (double)partials[i];
    sd[tid] = s;
    __syncthreads();
    for (int k = 128; k > 0; k >>= 1) {
        if (tid < k) sd[tid] += sd[tid + k];
        __syncthreads();
    }
    if (tid == 0) out[L_OFF] = (float)(2.0 * sd[0] / 16777216.0);
}

extern "C" void kernel_launch(void* const* d_in, const int* in_sizes, int n_in,
                              void* d_out, int out_size, void* d_ws, size_t ws_size,
                              hipStream_t stream) {
    const float* x  = (const float*)d_in[0];
    const float* cb = (const float*)d_in[1];
    float* out = (float*)d_out;
    char*  ws  = (char*)d_ws;
    float* ww  = (float*)ws;                          // 2048 B
    short* cbh = (short*)(ws + 2048);                 // 131072 B
    short* cbm = (short*)(ws + 2048 + 131072);        // 131072 B
    float* partials = (float*)(ws + 2048 + 262144);   // 4096 B

    prep_kernel<<<32, 256, 0, stream>>>(cb, ww, cbh, cbm);
    vq_main<<<NBLK, 256, 0, stream>>>(x, cb, ww, cbh, cbm, out, partials);
    loss_kernel<<<1, 256, 0, stream>>>(partials, out);
}